// Round 4
// baseline (1575.933 us; speedup 1.0000x reference)
//
#include <hip/hip_runtime.h>
#include <math.h>

#define B_DIM 128
#define T_DIM 50
#define LEAF  4880
#define A_DIM 64
#define ATTN  128
#define RNN   128
#define NC    283
#define M_TOT (B_DIM*T_DIM)   // 6400
#define KSPLIT 5
#define KTILES 122            // 4880 / 40

__device__ __forceinline__ float sigmoidf_(float x) {
  return 1.0f / (1.0f + __expf(-x));
}

// ---------------------------------------------------------------------------
// K1: partial[s][6400,128] = Ax[6400, kchunk] @ Wd[kchunk, 128]
// BM=32, BN=128, BK=40 (4880 = 122*40), 256 threads, grid (200, KSPLIT)
// ---------------------------------------------------------------------------
__global__ __launch_bounds__(256) void k_gemm_ksplit(
    const float* __restrict__ Ax, const float* __restrict__ Wd,
    float* __restrict__ P) {
  __shared__ __align__(16) float As[32][44];   // pad 40 -> 44
  __shared__ __align__(16) float Bs[40][128];
  const int tid = threadIdx.x;
  const int m0  = blockIdx.x * 32;
  const int s   = blockIdx.y;
  const int kt0 = (s * KTILES) / KSPLIT;
  const int kt1 = ((s + 1) * KTILES) / KSPLIT;
  const int ng  = tid & 31;   // n = ng*4
  const int mg  = tid >> 5;   // m = mg*4 + r

  const int rowA0 = tid / 10, k4A0 = tid % 10;
  const int rowA1 = (tid + 256) / 10, k4A1 = (tid + 256) % 10;
  const bool ph1 = (tid + 256) < 320;
  const float* pA0 = Ax + (size_t)(m0 + rowA0) * LEAF + kt0 * 40 + k4A0 * 4;
  const float* pA1 = Ax + (size_t)(m0 + rowA1) * LEAF + kt0 * 40 + k4A1 * 4;
  const int brb = tid >> 5, b4 = tid & 31;
  const float* pB = Wd + (size_t)kt0 * 40 * 128 + (size_t)brb * 128 + b4 * 4;

  float4 acc[4];
  #pragma unroll
  for (int r = 0; r < 4; ++r) acc[r] = make_float4(0.f, 0.f, 0.f, 0.f);

  for (int kt = kt0; kt < kt1; ++kt) {
    {
      float4 v = *(const float4*)pA0;
      *(float4*)&As[rowA0][k4A0 * 4] = v;
      if (ph1) {
        float4 w = *(const float4*)pA1;
        *(float4*)&As[rowA1][k4A1 * 4] = w;
      }
    }
    #pragma unroll
    for (int i = 0; i < 5; ++i) {
      float4 v = *(const float4*)(pB + (size_t)i * 8 * 128);
      *(float4*)&Bs[brb + i * 8][b4 * 4] = v;
    }
    __syncthreads();

    #pragma unroll
    for (int k = 0; k < 40; k += 4) {
      float4 av[4], bv[4];
      #pragma unroll
      for (int r = 0; r < 4; ++r) av[r] = *(const float4*)&As[mg * 4 + r][k];
      #pragma unroll
      for (int kk = 0; kk < 4; ++kk) bv[kk] = *(const float4*)&Bs[k + kk][ng * 4];
      #pragma unroll
      for (int r = 0; r < 4; ++r) {
        float aa[4] = {av[r].x, av[r].y, av[r].z, av[r].w};
        #pragma unroll
        for (int kk = 0; kk < 4; ++kk) {
          acc[r].x += aa[kk] * bv[kk].x;
          acc[r].y += aa[kk] * bv[kk].y;
          acc[r].z += aa[kk] * bv[kk].z;
          acc[r].w += aa[kk] * bv[kk].w;
        }
      }
    }
    __syncthreads();
    pA0 += 40; pA1 += 40; pB += 40 * 128;
  }

  float* out = P + (size_t)s * (M_TOT * 128);
  #pragma unroll
  for (int r = 0; r < 4; ++r)
    *(float4*)&out[(size_t)(m0 + mg * 4 + r) * 128 + ng * 4] = acc[r];
}

// ---------------------------------------------------------------------------
// Reduce KSPLIT partials + tanh (X aliases P slot 0; elementwise-safe).
// ---------------------------------------------------------------------------
__global__ __launch_bounds__(256) void k_reduce_tanh(
    float* __restrict__ P, float* __restrict__ X) {
  const size_t i = ((size_t)blockIdx.x * 256 + threadIdx.x) * 4;
  float4 a = *(const float4*)&P[i];
  #pragma unroll
  for (int s = 1; s < KSPLIT; ++s) {
    float4 b = *(const float4*)&P[(size_t)s * (M_TOT * 128) + i];
    a.x += b.x; a.y += b.y; a.z += b.z; a.w += b.w;
  }
  a.x = tanhf(a.x); a.y = tanhf(a.y); a.z = tanhf(a.z); a.w = tanhf(a.w);
  *(float4*)&X[i] = a;
}

// ---------------------------------------------------------------------------
// Generic small GEMM: C[M,N] = A[M,K] @ Bw[N,K]^T + bias  (opt sigmoid*mask)
// ---------------------------------------------------------------------------
template<int K, int ACT>
__global__ __launch_bounds__(256) void k_gemm_bn(
    const float* __restrict__ A, const float* __restrict__ Bw,
    const float* __restrict__ bias, const float* __restrict__ maskv,
    float* __restrict__ C, int N, int ldc) {
  __shared__ __align__(16) float As[32][K + 4];
  const int tid = threadIdx.x;
  const int m0 = blockIdx.x * 32;
  const int n0 = blockIdx.y * 64;
  constexpr int K4 = K / 4;

  #pragma unroll
  for (int i = 0; i < (32 * K4) / 256; ++i) {
    int idx = tid + i * 256;
    int row = idx / K4, k4 = idx % K4;
    float4 v = *(const float4*)&A[(size_t)(m0 + row) * K + k4 * 4];
    *(float4*)&As[row][k4 * 4] = v;
  }
  __syncthreads();

  const int n2 = tid & 31, mg = tid >> 5;
  const int n = n0 + n2 * 2;
  const int ns0 = min(n, N - 1), ns1 = min(n + 1, N - 1);
  const float* Bp0 = Bw + (size_t)ns0 * K;
  const float* Bp1 = Bw + (size_t)ns1 * K;

  float acc[4][2] = {};
  #pragma unroll 4
  for (int k = 0; k < K; k += 4) {
    float4 b0 = *(const float4*)&Bp0[k];
    float4 b1 = *(const float4*)&Bp1[k];
    #pragma unroll
    for (int r = 0; r < 4; ++r) {
      float4 a = *(const float4*)&As[mg * 4 + r][k];
      acc[r][0] += a.x * b0.x + a.y * b0.y + a.z * b0.z + a.w * b0.w;
      acc[r][1] += a.x * b1.x + a.y * b1.y + a.z * b1.z + a.w * b1.w;
    }
  }

  #pragma unroll
  for (int r = 0; r < 4; ++r) {
    int m = m0 + mg * 4 + r;
    #pragma unroll
    for (int c = 0; c < 2; ++c) {
      int nn = n + c;
      if (nn < N) {
        float v = acc[r][c] + bias[nn];
        if (ACT) v = sigmoidf_(v) * maskv[m];
        C[(size_t)m * ldc + nn] = v;
      }
    }
  }
}

// ---------------------------------------------------------------------------
// GRU scan v2 (fixed). One block per batch row; 512 threads.
// Thread t: j = t>>2 (output element), qf = t&3 (32-wide K slice).
// Each thread computes r,z,n partials for output j. Weights register-resident.
// NOTE: n-gate bias is INSIDE the r multiplication: n = tanh(xn + r*(Wn·h + bn))
// (R3 failure root cause: bias was applied outside -> absmax 1.56e-2).
// ---------------------------------------------------------------------------
__global__ __launch_bounds__(512) void k_gru(
    const float* __restrict__ xW, const float* __restrict__ Whh,
    const float* __restrict__ bhh, float* __restrict__ Hout) {
  const int b = blockIdx.x;
  const int tid = threadIdx.x;
  const int j  = tid >> 2;
  const int qf = tid & 3;
  __shared__ __align__(16) float hs[2][128];

  float4 wr[8], wz[8], wn[8];
  {
    const float* pr = Whh + (size_t)j * 128 + qf * 32;
    const float* pz = Whh + (size_t)(j + 128) * 128 + qf * 32;
    const float* pn = Whh + (size_t)(j + 256) * 128 + qf * 32;
    #pragma unroll
    for (int k = 0; k < 8; ++k) {
      wr[k] = *(const float4*)(pr + k * 4);
      wz[k] = *(const float4*)(pz + k * 4);
      wn[k] = *(const float4*)(pn + k * 4);
    }
  }
  const float br = bhh[j], bz = bhh[j + 128], bn_ = bhh[j + 256];

  if (tid < 128) hs[0][tid] = 0.0f;
  const float* xwb = xW + (size_t)b * 50 * 384;
  float xr = 0.f, xz = 0.f, xn = 0.f;
  if (qf == 0) { xr = xwb[j]; xz = xwb[128 + j]; xn = xwb[256 + j]; }
  __syncthreads();

  int cur = 0;
  for (int t = 0; t < 50; ++t) {
    // prefetch next step's input-gate values (independent of h)
    float nxr = 0.f, nxz = 0.f, nxn = 0.f;
    if (qf == 0 && t + 1 < 50) {
      const float* xwn = xwb + (size_t)(t + 1) * 384;
      nxr = xwn[j]; nxz = xwn[128 + j]; nxn = xwn[256 + j];
    }

    float ar = 0.f, az = 0.f, an = 0.f;
    #pragma unroll
    for (int k = 0; k < 8; ++k) {
      const int kk = (k + qf * 2) & 7;   // bank-rotated chunk
      float4 hv = *(const float4*)&hs[cur][qf * 32 + kk * 4];
      ar += wr[kk].x * hv.x + wr[kk].y * hv.y + wr[kk].z * hv.z + wr[kk].w * hv.w;
      az += wz[kk].x * hv.x + wz[kk].y * hv.y + wz[kk].z * hv.z + wz[kk].w * hv.w;
      an += wn[kk].x * hv.x + wn[kk].y * hv.y + wn[kk].z * hv.z + wn[kk].w * hv.w;
    }
    // butterfly over the 4-lane quad
    ar += __shfl_xor(ar, 1); ar += __shfl_xor(ar, 2);
    az += __shfl_xor(az, 1); az += __shfl_xor(az, 2);
    an += __shfl_xor(an, 1); an += __shfl_xor(an, 2);

    if (qf == 0) {
      float r = sigmoidf_(xr + ar + br);
      float z = sigmoidf_(xz + az + bz);
      float nn = tanhf(xn + r * (an + bn_));   // bias INSIDE r*
      float h = (1.f - z) * nn + z * hs[cur][j];
      hs[cur ^ 1][j] = h;
      Hout[(size_t)(b * 50 + t) * 128 + j] = h;
    }
    __syncthreads();
    cur ^= 1;
    xr = nxr; xz = nxz; xn = nxn;
  }
}

// ---------------------------------------------------------------------------
// Attention: per (b,t) block (6400 blocks, 128 threads).
// ---------------------------------------------------------------------------
__global__ __launch_bounds__(128) void k_attn(
    const float* __restrict__ H2, const int* __restrict__ F,
    const float* __restrict__ emb, float* __restrict__ S) {
  const int m = blockIdx.x;
  const int tid = threadIdx.x;
  __shared__ __align__(16) float outs[128];
  __shared__ __align__(16) float Ls[64][132];
  __shared__ float hls[64];
  __shared__ float wts[64];
  __shared__ int fs[64];

  outs[tid] = H2[(size_t)m * 128 + tid];
  if (tid < 64) fs[tid] = F[(size_t)m * 64 + tid];
  __syncthreads();

  #pragma unroll
  for (int i = 0; i < 16; ++i) {
    int idx = tid + i * 128;
    int a = idx >> 5, c4 = idx & 31;
    float4 v = *(const float4*)&emb[(size_t)fs[a] * 128 + c4 * 4];
    *(float4*)&Ls[a][c4 * 4] = v;
  }
  __syncthreads();

  {
    const int a = tid >> 1, hf = tid & 1;
    float sum = 0.f;
    #pragma unroll
    for (int j = 0; j < 16; ++j) {
      float4 lv = *(const float4*)&Ls[a][hf * 64 + j * 4];
      float4 ov = *(const float4*)&outs[hf * 64 + j * 4];
      sum += lv.x * ov.x + lv.y * ov.y + lv.z * ov.z + lv.w * ov.w;
    }
    float other = __shfl_xor(sum, 1);
    sum += other;
    if (hf == 0) hls[a] = sum + (fs[a] > 0 ? 0.0f : -1e30f);
  }
  __syncthreads();

  if (tid < 64) {
    float v = hls[tid];
    float mx = v;
    #pragma unroll
    for (int o = 32; o; o >>= 1) mx = fmaxf(mx, __shfl_xor(mx, o));
    float e = __expf(v - mx);
    float sm = e;
    #pragma unroll
    for (int o = 32; o; o >>= 1) sm += __shfl_xor(sm, o);
    wts[tid] = e / sm;
  }
  __syncthreads();

  float kv = 0.f;
  #pragma unroll 8
  for (int a2 = 0; a2 < 64; ++a2) kv += wts[a2] * Ls[a2][tid];

  S[(size_t)m * 256 + tid] = outs[tid];
  S[(size_t)m * 256 + 128 + tid] = kv;
}

// ---------------------------------------------------------------------------
extern "C" void kernel_launch(void* const* d_in, const int* in_sizes, int n_in,
                              void* d_out, int out_size, void* d_ws, size_t ws_size,
                              hipStream_t stream) {
  const float* inputs_x  = (const float*)d_in[0];
  const int*   inputs_f  = (const int*)d_in[1];
  const float* mask_seqs = (const float*)d_in[2];
  const float* dag_emb   = (const float*)d_in[3];
  const float* embed_a   = (const float*)d_in[4];
  const float* Wih0 = (const float*)d_in[5];
  const float* Whh0 = (const float*)d_in[6];
  const float* bih0 = (const float*)d_in[7];
  const float* bhh0 = (const float*)d_in[8];
  const float* Wih1 = (const float*)d_in[9];
  const float* Whh1 = (const float*)d_in[10];
  const float* bih1 = (const float*)d_in[11];
  const float* bhh1 = (const float*)d_in[12];
  const float* fc_w = (const float*)d_in[13];
  const float* fc_b = (const float*)d_in[14];
  float* out = (float*)d_out;

  float* ws = (float*)d_ws;
  float* P  = ws;
  float* X  = P;                       // aliases P slot 0
  float* S  = P + 819200;              // aliases P slots 1-2
  float* xW = ws + KSPLIT * 819200;
  float* H1 = xW + 2457600;
  float* H2 = H1 + 819200;

  k_gemm_ksplit<<<dim3(200, KSPLIT), 256, 0, stream>>>(inputs_x, dag_emb, P);
  k_reduce_tanh<<<800, 256, 0, stream>>>(P, X);
  k_gemm_bn<128, 0><<<dim3(200, 6), 256, 0, stream>>>(X, Wih0, bih0, nullptr, xW, 384, 384);
  k_gru<<<128, 512, 0, stream>>>(xW, Whh0, bhh0, H1);
  k_gemm_bn<128, 0><<<dim3(200, 6), 256, 0, stream>>>(H1, Wih1, bih1, nullptr, xW, 384, 384);
  k_gru<<<128, 512, 0, stream>>>(xW, Whh1, bhh1, H2);
  k_attn<<<6400, 128, 0, stream>>>(H2, inputs_f, embed_a, S);
  k_gemm_bn<256, 1><<<dim3(200, 5), 256, 0, stream>>>(S, fc_w, fc_b, mask_seqs, out, 283, 283);
}

// Round 5
// 562.356 us; speedup vs baseline: 2.8024x; 2.8024x over previous
//
#include <hip/hip_runtime.h>
#include <math.h>

#define B_DIM 128
#define T_DIM 50
#define LEAF  4880
#define A_DIM 64
#define ATTN  128
#define RNN   128
#define NC    283
#define M_TOT (B_DIM*T_DIM)   // 6400
#define KSPLIT 5
#define KTILES 122            // 4880 / 40

__device__ __forceinline__ float sigmoidf_(float x) {
  return 1.0f / (1.0f + __expf(-x));
}

// ---------------------------------------------------------------------------
// K1: partial[s][6400,128] = Ax[6400, kchunk] @ Wd[kchunk, 128]
// BM=32, BN=128, BK=40 (4880 = 122*40), 256 threads, grid (200, KSPLIT)
// ---------------------------------------------------------------------------
__global__ __launch_bounds__(256) void k_gemm_ksplit(
    const float* __restrict__ Ax, const float* __restrict__ Wd,
    float* __restrict__ P) {
  __shared__ __align__(16) float As[32][44];   // pad 40 -> 44
  __shared__ __align__(16) float Bs[40][128];
  const int tid = threadIdx.x;
  const int m0  = blockIdx.x * 32;
  const int s   = blockIdx.y;
  const int kt0 = (s * KTILES) / KSPLIT;
  const int kt1 = ((s + 1) * KTILES) / KSPLIT;
  const int ng  = tid & 31;   // n = ng*4
  const int mg  = tid >> 5;   // m = mg*4 + r

  const int rowA0 = tid / 10, k4A0 = tid % 10;
  const int rowA1 = (tid + 256) / 10, k4A1 = (tid + 256) % 10;
  const bool ph1 = (tid + 256) < 320;
  const float* pA0 = Ax + (size_t)(m0 + rowA0) * LEAF + kt0 * 40 + k4A0 * 4;
  const float* pA1 = Ax + (size_t)(m0 + rowA1) * LEAF + kt0 * 40 + k4A1 * 4;
  const int brb = tid >> 5, b4 = tid & 31;
  const float* pB = Wd + (size_t)kt0 * 40 * 128 + (size_t)brb * 128 + b4 * 4;

  float4 acc[4];
  #pragma unroll
  for (int r = 0; r < 4; ++r) acc[r] = make_float4(0.f, 0.f, 0.f, 0.f);

  for (int kt = kt0; kt < kt1; ++kt) {
    {
      float4 v = *(const float4*)pA0;
      *(float4*)&As[rowA0][k4A0 * 4] = v;
      if (ph1) {
        float4 w = *(const float4*)pA1;
        *(float4*)&As[rowA1][k4A1 * 4] = w;
      }
    }
    #pragma unroll
    for (int i = 0; i < 5; ++i) {
      float4 v = *(const float4*)(pB + (size_t)i * 8 * 128);
      *(float4*)&Bs[brb + i * 8][b4 * 4] = v;
    }
    __syncthreads();

    #pragma unroll
    for (int k = 0; k < 40; k += 4) {
      float4 av[4], bv[4];
      #pragma unroll
      for (int r = 0; r < 4; ++r) av[r] = *(const float4*)&As[mg * 4 + r][k];
      #pragma unroll
      for (int kk = 0; kk < 4; ++kk) bv[kk] = *(const float4*)&Bs[k + kk][ng * 4];
      #pragma unroll
      for (int r = 0; r < 4; ++r) {
        float aa[4] = {av[r].x, av[r].y, av[r].z, av[r].w};
        #pragma unroll
        for (int kk = 0; kk < 4; ++kk) {
          acc[r].x += aa[kk] * bv[kk].x;
          acc[r].y += aa[kk] * bv[kk].y;
          acc[r].z += aa[kk] * bv[kk].z;
          acc[r].w += aa[kk] * bv[kk].w;
        }
      }
    }
    __syncthreads();
    pA0 += 40; pA1 += 40; pB += 40 * 128;
  }

  float* out = P + (size_t)s * (M_TOT * 128);
  #pragma unroll
  for (int r = 0; r < 4; ++r)
    *(float4*)&out[(size_t)(m0 + mg * 4 + r) * 128 + ng * 4] = acc[r];
}

// ---------------------------------------------------------------------------
// Reduce KSPLIT partials + tanh (X aliases P slot 0; elementwise-safe).
// ---------------------------------------------------------------------------
__global__ __launch_bounds__(256) void k_reduce_tanh(
    float* __restrict__ P, float* __restrict__ X) {
  const size_t i = ((size_t)blockIdx.x * 256 + threadIdx.x) * 4;
  float4 a = *(const float4*)&P[i];
  #pragma unroll
  for (int s = 1; s < KSPLIT; ++s) {
    float4 b = *(const float4*)&P[(size_t)s * (M_TOT * 128) + i];
    a.x += b.x; a.y += b.y; a.z += b.z; a.w += b.w;
  }
  a.x = tanhf(a.x); a.y = tanhf(a.y); a.z = tanhf(a.z); a.w = tanhf(a.w);
  *(float4*)&X[i] = a;
}

// ---------------------------------------------------------------------------
// Generic small GEMM: C[M,N] = A[M,K] @ Bw[N,K]^T + bias  (opt sigmoid*mask)
// ---------------------------------------------------------------------------
template<int K, int ACT>
__global__ __launch_bounds__(256) void k_gemm_bn(
    const float* __restrict__ A, const float* __restrict__ Bw,
    const float* __restrict__ bias, const float* __restrict__ maskv,
    float* __restrict__ C, int N, int ldc) {
  __shared__ __align__(16) float As[32][K + 4];
  const int tid = threadIdx.x;
  const int m0 = blockIdx.x * 32;
  const int n0 = blockIdx.y * 64;
  constexpr int K4 = K / 4;

  #pragma unroll
  for (int i = 0; i < (32 * K4) / 256; ++i) {
    int idx = tid + i * 256;
    int row = idx / K4, k4 = idx % K4;
    float4 v = *(const float4*)&A[(size_t)(m0 + row) * K + k4 * 4];
    *(float4*)&As[row][k4 * 4] = v;
  }
  __syncthreads();

  const int n2 = tid & 31, mg = tid >> 5;
  const int n = n0 + n2 * 2;
  const int ns0 = min(n, N - 1), ns1 = min(n + 1, N - 1);
  const float* Bp0 = Bw + (size_t)ns0 * K;
  const float* Bp1 = Bw + (size_t)ns1 * K;

  float acc[4][2] = {};
  #pragma unroll 4
  for (int k = 0; k < K; k += 4) {
    float4 b0 = *(const float4*)&Bp0[k];
    float4 b1 = *(const float4*)&Bp1[k];
    #pragma unroll
    for (int r = 0; r < 4; ++r) {
      float4 a = *(const float4*)&As[mg * 4 + r][k];
      acc[r][0] += a.x * b0.x + a.y * b0.y + a.z * b0.z + a.w * b0.w;
      acc[r][1] += a.x * b1.x + a.y * b1.y + a.z * b1.z + a.w * b1.w;
    }
  }

  #pragma unroll
  for (int r = 0; r < 4; ++r) {
    int m = m0 + mg * 4 + r;
    #pragma unroll
    for (int c = 0; c < 2; ++c) {
      int nn = n + c;
      if (nn < N) {
        float v = acc[r][c] + bias[nn];
        if (ACT) v = sigmoidf_(v) * maskv[m];
        C[(size_t)m * ldc + nn] = v;
      }
    }
  }
}

// ---------------------------------------------------------------------------
// GRU scan v3. One block per batch row; 512 threads.
// Thread t: j = t>>2 (output element), qf = t&3 (32-wide K slice).
// Weights are PRE-ROTATED at load (slot k holds chunk (k+2qf)&7) so the
// register arrays are only ever indexed by the unroll-constant k — R4's
// runtime index wr[kk] spilled all 96 weight VGPRs to scratch (VGPR_Count 56,
// 24 MB spill writes/dispatch, 579 us). LDS address carries the rotation
// instead (runtime LDS addresses are free); quads still hit disjoint bank
// groups at each k -> conflict-free. n-gate bias INSIDE r*: n=tanh(xn+r*(Wn.h+bn)).
// ---------------------------------------------------------------------------
__global__ __launch_bounds__(512) void k_gru(
    const float* __restrict__ xW, const float* __restrict__ Whh,
    const float* __restrict__ bhh, float* __restrict__ Hout) {
  const int b = blockIdx.x;
  const int tid = threadIdx.x;
  const int j  = tid >> 2;
  const int qf = tid & 3;
  __shared__ __align__(16) float hs[2][128];

  float4 wr[8], wz[8], wn[8];
  {
    const float* pr = Whh + (size_t)j * 128 + qf * 32;
    const float* pz = Whh + (size_t)(j + 128) * 128 + qf * 32;
    const float* pn = Whh + (size_t)(j + 256) * 128 + qf * 32;
    #pragma unroll
    for (int k = 0; k < 8; ++k) {
      const int c = (k + qf * 2) & 7;   // rotation folded into the LOAD
      wr[k] = *(const float4*)(pr + c * 4);
      wz[k] = *(const float4*)(pz + c * 4);
      wn[k] = *(const float4*)(pn + c * 4);
    }
  }
  const float br = bhh[j], bz = bhh[j + 128], bn_ = bhh[j + 256];

  if (tid < 128) hs[0][tid] = 0.0f;
  const float* xwb = xW + (size_t)b * 50 * 384;
  float xr = 0.f, xz = 0.f, xn = 0.f;
  if (qf == 0) { xr = xwb[j]; xz = xwb[128 + j]; xn = xwb[256 + j]; }
  __syncthreads();

  int cur = 0;
  for (int t = 0; t < 50; ++t) {
    // prefetch next step's input-gate values (independent of h)
    float nxr = 0.f, nxz = 0.f, nxn = 0.f;
    if (qf == 0 && t + 1 < 50) {
      const float* xwn = xwb + (size_t)(t + 1) * 384;
      nxr = xwn[j]; nxz = xwn[128 + j]; nxn = xwn[256 + j];
    }

    float ar = 0.f, az = 0.f, an = 0.f;
    #pragma unroll
    for (int k = 0; k < 8; ++k) {
      const int c = (k + qf * 2) & 7;   // runtime -> LDS address only
      float4 hv = *(const float4*)&hs[cur][qf * 32 + c * 4];
      ar += wr[k].x * hv.x + wr[k].y * hv.y + wr[k].z * hv.z + wr[k].w * hv.w;
      az += wz[k].x * hv.x + wz[k].y * hv.y + wz[k].z * hv.z + wz[k].w * hv.w;
      an += wn[k].x * hv.x + wn[k].y * hv.y + wn[k].z * hv.z + wn[k].w * hv.w;
    }
    // butterfly over the 4-lane quad
    ar += __shfl_xor(ar, 1); ar += __shfl_xor(ar, 2);
    az += __shfl_xor(az, 1); az += __shfl_xor(az, 2);
    an += __shfl_xor(an, 1); an += __shfl_xor(an, 2);

    if (qf == 0) {
      float r = sigmoidf_(xr + ar + br);
      float z = sigmoidf_(xz + az + bz);
      float nn = tanhf(xn + r * (an + bn_));   // bias INSIDE r*
      float h = (1.f - z) * nn + z * hs[cur][j];
      hs[cur ^ 1][j] = h;
      Hout[(size_t)(b * 50 + t) * 128 + j] = h;
    }
    __syncthreads();
    cur ^= 1;
    xr = nxr; xz = nxz; xn = nxn;
  }
}

// ---------------------------------------------------------------------------
// Attention: per (b,t) block (6400 blocks, 128 threads).
// ---------------------------------------------------------------------------
__global__ __launch_bounds__(128) void k_attn(
    const float* __restrict__ H2, const int* __restrict__ F,
    const float* __restrict__ emb, float* __restrict__ S) {
  const int m = blockIdx.x;
  const int tid = threadIdx.x;
  __shared__ __align__(16) float outs[128];
  __shared__ __align__(16) float Ls[64][132];
  __shared__ float hls[64];
  __shared__ float wts[64];
  __shared__ int fs[64];

  outs[tid] = H2[(size_t)m * 128 + tid];
  if (tid < 64) fs[tid] = F[(size_t)m * 64 + tid];
  __syncthreads();

  #pragma unroll
  for (int i = 0; i < 16; ++i) {
    int idx = tid + i * 128;
    int a = idx >> 5, c4 = idx & 31;
    float4 v = *(const float4*)&emb[(size_t)fs[a] * 128 + c4 * 4];
    *(float4*)&Ls[a][c4 * 4] = v;
  }
  __syncthreads();

  {
    const int a = tid >> 1, hf = tid & 1;
    float sum = 0.f;
    #pragma unroll
    for (int j = 0; j < 16; ++j) {
      float4 lv = *(const float4*)&Ls[a][hf * 64 + j * 4];
      float4 ov = *(const float4*)&outs[hf * 64 + j * 4];
      sum += lv.x * ov.x + lv.y * ov.y + lv.z * ov.z + lv.w * ov.w;
    }
    float other = __shfl_xor(sum, 1);
    sum += other;
    if (hf == 0) hls[a] = sum + (fs[a] > 0 ? 0.0f : -1e30f);
  }
  __syncthreads();

  if (tid < 64) {
    float v = hls[tid];
    float mx = v;
    #pragma unroll
    for (int o = 32; o; o >>= 1) mx = fmaxf(mx, __shfl_xor(mx, o));
    float e = __expf(v - mx);
    float sm = e;
    #pragma unroll
    for (int o = 32; o; o >>= 1) sm += __shfl_xor(sm, o);
    wts[tid] = e / sm;
  }
  __syncthreads();

  float kv = 0.f;
  #pragma unroll 8
  for (int a2 = 0; a2 < 64; ++a2) kv += wts[a2] * Ls[a2][tid];

  S[(size_t)m * 256 + tid] = outs[tid];
  S[(size_t)m * 256 + 128 + tid] = kv;
}

// ---------------------------------------------------------------------------
extern "C" void kernel_launch(void* const* d_in, const int* in_sizes, int n_in,
                              void* d_out, int out_size, void* d_ws, size_t ws_size,
                              hipStream_t stream) {
  const float* inputs_x  = (const float*)d_in[0];
  const int*   inputs_f  = (const int*)d_in[1];
  const float* mask_seqs = (const float*)d_in[2];
  const float* dag_emb   = (const float*)d_in[3];
  const float* embed_a   = (const float*)d_in[4];
  const float* Wih0 = (const float*)d_in[5];
  const float* Whh0 = (const float*)d_in[6];
  const float* bih0 = (const float*)d_in[7];
  const float* bhh0 = (const float*)d_in[8];
  const float* Wih1 = (const float*)d_in[9];
  const float* Whh1 = (const float*)d_in[10];
  const float* bih1 = (const float*)d_in[11];
  const float* bhh1 = (const float*)d_in[12];
  const float* fc_w = (const float*)d_in[13];
  const float* fc_b = (const float*)d_in[14];
  float* out = (float*)d_out;

  float* ws = (float*)d_ws;
  float* P  = ws;
  float* X  = P;                       // aliases P slot 0
  float* S  = P + 819200;              // aliases P slots 1-2
  float* xW = ws + KSPLIT * 819200;
  float* H1 = xW + 2457600;
  float* H2 = H1 + 819200;

  k_gemm_ksplit<<<dim3(200, KSPLIT), 256, 0, stream>>>(inputs_x, dag_emb, P);
  k_reduce_tanh<<<800, 256, 0, stream>>>(P, X);
  k_gemm_bn<128, 0><<<dim3(200, 6), 256, 0, stream>>>(X, Wih0, bih0, nullptr, xW, 384, 384);
  k_gru<<<128, 512, 0, stream>>>(xW, Whh0, bhh0, H1);
  k_gemm_bn<128, 0><<<dim3(200, 6), 256, 0, stream>>>(H1, Wih1, bih1, nullptr, xW, 384, 384);
  k_gru<<<128, 512, 0, stream>>>(xW, Whh1, bhh1, H2);
  k_attn<<<6400, 128, 0, stream>>>(H2, inputs_f, embed_a, S);
  k_gemm_bn<256, 1><<<dim3(200, 5), 256, 0, stream>>>(S, fc_w, fc_b, mask_seqs, out, 283, 283);
}

// Round 6
// 519.067 us; speedup vs baseline: 3.0361x; 1.0834x over previous
//
#include <hip/hip_runtime.h>
#include <math.h>

#define B_DIM 128
#define T_DIM 50
#define LEAF  4880
#define A_DIM 64
#define ATTN  128
#define RNN   128
#define NC    283
#define M_TOT (B_DIM*T_DIM)   // 6400
#define KSPLIT 5
#define NCH 153               // ceil(4880/32); chunk 152 has 16 valid k
#define WT_PLANE (NCH*512*8)  // 626688 ushort per plane (hi / lo)

using short8 = __attribute__((ext_vector_type(8))) short;
using f32x4  = __attribute__((ext_vector_type(4))) float;

__device__ __forceinline__ float sigmoidf_(float x) {
  return 1.0f / (1.0f + __expf(-x));
}

// RNE fp32 -> bf16 bits (standard bit trick; valid for all finite values)
__device__ __forceinline__ unsigned short f32_to_bf16_rne(float f) {
  unsigned int u = __float_as_uint(f);
  unsigned int r = u + 0x7FFFu + ((u >> 16) & 1u);
  return (unsigned short)(r >> 16);
}
__device__ __forceinline__ float bf16_bits_to_f32(unsigned short b) {
  return __uint_as_float(((unsigned int)b) << 16);
}

// ---------------------------------------------------------------------------
// Pre-transpose W[4880,128] into MFMA B-fragment order, hi/lo bf16 planes.
// Wt[plane][c][nt][lane][j]: lane holds W[k = c*32 + (lane>>4)*8 + j][nt*16 + (lane&15)]
// (zero-padded for k >= 4880). 306 blocks x 256 thr; one 16B slot per thread/plane.
// ---------------------------------------------------------------------------
__global__ __launch_bounds__(256) void k_prep_wt(
    const float* __restrict__ Wd, unsigned short* __restrict__ Wt) {
  const int u = blockIdx.x * 256 + threadIdx.x;   // 0 .. 78335 (NCH*512)
  const int c = u >> 9, rem = u & 511;
  const int nt = rem >> 6, lane = rem & 63;
  const int n = nt * 16 + (lane & 15);
  const int kb = c * 32 + ((lane >> 4) << 3);
  short8 h8, l8;
  #pragma unroll
  for (int j = 0; j < 8; ++j) {
    int k = kb + j;
    float v = (k < LEAF) ? Wd[(size_t)k * 128 + n] : 0.0f;
    unsigned short hb = f32_to_bf16_rne(v);
    unsigned short lb = f32_to_bf16_rne(v - bf16_bits_to_f32(hb));
    h8[j] = (short)hb;
    l8[j] = (short)lb;
  }
  *(short8*)&Wt[(size_t)u * 8] = h8;
  *(short8*)&Wt[(size_t)WT_PLANE + (size_t)u * 8] = l8;
}

// ---------------------------------------------------------------------------
// Big GEMM via MFMA: P[s][6400,128] = Ax[6400,kchunk] (.) Wd[kchunk,128]
// hi/lo bf16 split: A*W ~= Ahi*Whi + Alo*Whi + Ahi*Wlo (fp32-level accuracy;
// dropped Alo*Wlo <= 2^-18 relative). BM=64, BN=128, BK=32, 256 thr (4 waves),
// grid (100, KSPLIT). A staged fragment-permuted (lane-linear 16B -> conflict-
// free b128); W staged by copying the pre-transposed Wt. All register arrays
// indexed by unroll constants only (R4 lesson: runtime idx -> scratch spill).
// ---------------------------------------------------------------------------
__global__ __launch_bounds__(256) void k_gemm_mfma(
    const float* __restrict__ Ax, const unsigned short* __restrict__ Wt,
    float* __restrict__ P) {
  __shared__ __align__(16) unsigned short As[2 * 4 * 64 * 8];  // hi|lo planes, 8 KB
  __shared__ __align__(16) unsigned short Bs[2 * 8 * 64 * 8];  // hi|lo planes, 16 KB
  const int tid  = threadIdx.x;
  const int lane = tid & 63;
  const int w    = tid >> 6;
  const int M0   = blockIdx.x * 64;
  const int s    = blockIdx.y;
  const int c0   = (s * NCH) / KSPLIT;
  const int c1   = ((s + 1) * NCH) / KSPLIT;

  // A staging map: thread -> row am = tid>>2, k-quad aq = tid&3 (8 k each).
  // Dest slot (sub=am>>4, fragment lane (am&15)+16*aq) is a bijection per wave
  // -> contiguous 1KB b128 writes, conflict-free.
  const int am = tid >> 2;
  const int aq = tid & 3;
  const float* pA = Ax + (size_t)(M0 + am) * LEAF + aq * 8;
  const int a_dst = (((am >> 4) * 64) + (am & 15) + 16 * aq) * 8;

  f32x4 acc[8];
  #pragma unroll
  for (int nt = 0; nt < 8; ++nt) {
    #pragma unroll
    for (int q = 0; q < 4; ++q) acc[nt][q] = 0.0f;
  }

  for (int c = c0; c < c1; ++c) {
    // ---- stage A tile (fp32 -> hi/lo bf16, fragment-permuted) ----
    {
      const int kg = c * 32 + aq * 8;
      float v[8];
      if (kg + 8 <= LEAF) {
        float4 v0 = *(const float4*)(pA + (size_t)c * 32);
        float4 v1 = *(const float4*)(pA + (size_t)c * 32 + 4);
        v[0] = v0.x; v[1] = v0.y; v[2] = v0.z; v[3] = v0.w;
        v[4] = v1.x; v[5] = v1.y; v[6] = v1.z; v[7] = v1.w;
      } else {
        #pragma unroll
        for (int j = 0; j < 8; ++j)
          v[j] = (kg + j < LEAF) ? pA[(size_t)c * 32 + j] : 0.0f;
      }
      short8 h8, l8;
      #pragma unroll
      for (int j = 0; j < 8; ++j) {
        unsigned short hb = f32_to_bf16_rne(v[j]);
        unsigned short lb = f32_to_bf16_rne(v[j] - bf16_bits_to_f32(hb));
        h8[j] = (short)hb;
        l8[j] = (short)lb;
      }
      *(short8*)&As[a_dst] = h8;
      *(short8*)&As[2048 + a_dst] = l8;
    }
    // ---- stage B tile: straight 16B copies from pre-transposed Wt ----
    #pragma unroll
    for (int i = 0; i < 4; ++i) {
      const int u = tid + i * 256;          // 0..1023: plane = u>>9, slot = u&511
      const int plane = u >> 9, slot = u & 511;
      short8 bv = *(const short8*)&Wt[(size_t)plane * WT_PLANE +
                                      ((size_t)c * 512 + slot) * 8];
      *(short8*)&Bs[plane * 4096 + slot * 8] = bv;
    }
    __syncthreads();

    // ---- compute: 2 + 16 ds_read_b128, 24 MFMA per wave ----
    short8 a_hi = *(const short8*)&As[(w * 64 + lane) * 8];
    short8 a_lo = *(const short8*)&As[2048 + (w * 64 + lane) * 8];
    #pragma unroll
    for (int nt = 0; nt < 8; ++nt) {
      short8 b_hi = *(const short8*)&Bs[(nt * 64 + lane) * 8];
      short8 b_lo = *(const short8*)&Bs[4096 + (nt * 64 + lane) * 8];
      acc[nt] = __builtin_amdgcn_mfma_f32_16x16x32_bf16(a_hi, b_lo, acc[nt], 0, 0, 0);
      acc[nt] = __builtin_amdgcn_mfma_f32_16x16x32_bf16(a_lo, b_hi, acc[nt], 0, 0, 0);
      acc[nt] = __builtin_amdgcn_mfma_f32_16x16x32_bf16(a_hi, b_hi, acc[nt], 0, 0, 0);
    }
    __syncthreads();
  }

  // epilogue: C/D layout col=lane&15, row=(lane>>4)*4+r
  float* outp = P + (size_t)s * ((size_t)M_TOT * 128);
  const int mrow = M0 + w * 16 + ((lane >> 4) << 2);
  const int col = lane & 15;
  #pragma unroll
  for (int nt = 0; nt < 8; ++nt) {
    #pragma unroll
    for (int r = 0; r < 4; ++r)
      outp[(size_t)(mrow + r) * 128 + nt * 16 + col] = acc[nt][r];
  }
}

// ---------------------------------------------------------------------------
// Reduce KSPLIT partials + tanh (X aliases P slot 0; elementwise-safe).
// ---------------------------------------------------------------------------
__global__ __launch_bounds__(256) void k_reduce_tanh(
    float* __restrict__ P, float* __restrict__ X) {
  const size_t i = ((size_t)blockIdx.x * 256 + threadIdx.x) * 4;
  float4 a = *(const float4*)&P[i];
  #pragma unroll
  for (int s = 1; s < KSPLIT; ++s) {
    float4 b = *(const float4*)&P[(size_t)s * (M_TOT * 128) + i];
    a.x += b.x; a.y += b.y; a.z += b.z; a.w += b.w;
  }
  a.x = tanhf(a.x); a.y = tanhf(a.y); a.z = tanhf(a.z); a.w = tanhf(a.w);
  *(float4*)&X[i] = a;
}

// ---------------------------------------------------------------------------
// Generic small GEMM: C[M,N] = A[M,K] @ Bw[N,K]^T + bias  (opt sigmoid*mask)
// ---------------------------------------------------------------------------
template<int K, int ACT>
__global__ __launch_bounds__(256) void k_gemm_bn(
    const float* __restrict__ A, const float* __restrict__ Bw,
    const float* __restrict__ bias, const float* __restrict__ maskv,
    float* __restrict__ C, int N, int ldc) {
  __shared__ __align__(16) float Asm[32][K + 4];
  const int tid = threadIdx.x;
  const int m0 = blockIdx.x * 32;
  const int n0 = blockIdx.y * 64;
  constexpr int K4 = K / 4;

  #pragma unroll
  for (int i = 0; i < (32 * K4) / 256; ++i) {
    int idx = tid + i * 256;
    int row = idx / K4, k4 = idx % K4;
    float4 v = *(const float4*)&A[(size_t)(m0 + row) * K + k4 * 4];
    *(float4*)&Asm[row][k4 * 4] = v;
  }
  __syncthreads();

  const int n2 = tid & 31, mg = tid >> 5;
  const int n = n0 + n2 * 2;
  const int ns0 = min(n, N - 1), ns1 = min(n + 1, N - 1);
  const float* Bp0 = Bw + (size_t)ns0 * K;
  const float* Bp1 = Bw + (size_t)ns1 * K;

  float acc[4][2] = {};
  #pragma unroll 4
  for (int k = 0; k < K; k += 4) {
    float4 b0 = *(const float4*)&Bp0[k];
    float4 b1 = *(const float4*)&Bp1[k];
    #pragma unroll
    for (int r = 0; r < 4; ++r) {
      float4 a = *(const float4*)&Asm[mg * 4 + r][k];
      acc[r][0] += a.x * b0.x + a.y * b0.y + a.z * b0.z + a.w * b0.w;
      acc[r][1] += a.x * b1.x + a.y * b1.y + a.z * b1.z + a.w * b1.w;
    }
  }

  #pragma unroll
  for (int r = 0; r < 4; ++r) {
    int m = m0 + mg * 4 + r;
    #pragma unroll
    for (int c = 0; c < 2; ++c) {
      int nn = n + c;
      if (nn < N) {
        float v = acc[r][c] + bias[nn];
        if (ACT) v = sigmoidf_(v) * maskv[m];
        C[(size_t)m * ldc + nn] = v;
      }
    }
  }
}

// ---------------------------------------------------------------------------
// GRU scan v3 (R5-proven). One block per batch row; 512 threads.
// Weights pre-rotated at load so register arrays use unroll-constant indices
// only (R4: runtime idx -> scratch spill). n-gate bias INSIDE r*:
// n = tanh(xn + r*(Wn.h + bn)).
// ---------------------------------------------------------------------------
__global__ __launch_bounds__(512) void k_gru(
    const float* __restrict__ xW, const float* __restrict__ Whh,
    const float* __restrict__ bhh, float* __restrict__ Hout) {
  const int b = blockIdx.x;
  const int tid = threadIdx.x;
  const int j  = tid >> 2;
  const int qf = tid & 3;
  __shared__ __align__(16) float hs[2][128];

  float4 wr[8], wz[8], wn[8];
  {
    const float* pr = Whh + (size_t)j * 128 + qf * 32;
    const float* pz = Whh + (size_t)(j + 128) * 128 + qf * 32;
    const float* pn = Whh + (size_t)(j + 256) * 128 + qf * 32;
    #pragma unroll
    for (int k = 0; k < 8; ++k) {
      const int c = (k + qf * 2) & 7;   // rotation folded into the LOAD
      wr[k] = *(const float4*)(pr + c * 4);
      wz[k] = *(const float4*)(pz + c * 4);
      wn[k] = *(const float4*)(pn + c * 4);
    }
  }
  const float br = bhh[j], bz = bhh[j + 128], bn_ = bhh[j + 256];

  if (tid < 128) hs[0][tid] = 0.0f;
  const float* xwb = xW + (size_t)b * 50 * 384;
  float xr = 0.f, xz = 0.f, xn = 0.f;
  if (qf == 0) { xr = xwb[j]; xz = xwb[128 + j]; xn = xwb[256 + j]; }
  __syncthreads();

  int cur = 0;
  for (int t = 0; t < 50; ++t) {
    float nxr = 0.f, nxz = 0.f, nxn = 0.f;
    if (qf == 0 && t + 1 < 50) {
      const float* xwn = xwb + (size_t)(t + 1) * 384;
      nxr = xwn[j]; nxz = xwn[128 + j]; nxn = xwn[256 + j];
    }

    float ar = 0.f, az = 0.f, an = 0.f;
    #pragma unroll
    for (int k = 0; k < 8; ++k) {
      const int c = (k + qf * 2) & 7;   // runtime -> LDS address only
      float4 hv = *(const float4*)&hs[cur][qf * 32 + c * 4];
      ar += wr[k].x * hv.x + wr[k].y * hv.y + wr[k].z * hv.z + wr[k].w * hv.w;
      az += wz[k].x * hv.x + wz[k].y * hv.y + wz[k].z * hv.z + wz[k].w * hv.w;
      an += wn[k].x * hv.x + wn[k].y * hv.y + wn[k].z * hv.z + wn[k].w * hv.w;
    }
    ar += __shfl_xor(ar, 1); ar += __shfl_xor(ar, 2);
    az += __shfl_xor(az, 1); az += __shfl_xor(az, 2);
    an += __shfl_xor(an, 1); an += __shfl_xor(an, 2);

    if (qf == 0) {
      float r = sigmoidf_(xr + ar + br);
      float z = sigmoidf_(xz + az + bz);
      float nn = tanhf(xn + r * (an + bn_));   // bias INSIDE r*
      float h = (1.f - z) * nn + z * hs[cur][j];
      hs[cur ^ 1][j] = h;
      Hout[(size_t)(b * 50 + t) * 128 + j] = h;
    }
    __syncthreads();
    cur ^= 1;
    xr = nxr; xz = nxz; xn = nxn;
  }
}

// ---------------------------------------------------------------------------
// Attention: per (b,t) block (6400 blocks, 128 threads).
// ---------------------------------------------------------------------------
__global__ __launch_bounds__(128) void k_attn(
    const float* __restrict__ H2, const int* __restrict__ F,
    const float* __restrict__ emb, float* __restrict__ S) {
  const int m = blockIdx.x;
  const int tid = threadIdx.x;
  __shared__ __align__(16) float outs[128];
  __shared__ __align__(16) float Ls[64][132];
  __shared__ float hls[64];
  __shared__ float wts[64];
  __shared__ int fs[64];

  outs[tid] = H2[(size_t)m * 128 + tid];
  if (tid < 64) fs[tid] = F[(size_t)m * 64 + tid];
  __syncthreads();

  #pragma unroll
  for (int i = 0; i < 16; ++i) {
    int idx = tid + i * 128;
    int a = idx >> 5, c4 = idx & 31;
    float4 v = *(const float4*)&emb[(size_t)fs[a] * 128 + c4 * 4];
    *(float4*)&Ls[a][c4 * 4] = v;
  }
  __syncthreads();

  {
    const int a = tid >> 1, hf = tid & 1;
    float sum = 0.f;
    #pragma unroll
    for (int j = 0; j < 16; ++j) {
      float4 lv = *(const float4*)&Ls[a][hf * 64 + j * 4];
      float4 ov = *(const float4*)&outs[hf * 64 + j * 4];
      sum += lv.x * ov.x + lv.y * ov.y + lv.z * ov.z + lv.w * ov.w;
    }
    float other = __shfl_xor(sum, 1);
    sum += other;
    if (hf == 0) hls[a] = sum + (fs[a] > 0 ? 0.0f : -1e30f);
  }
  __syncthreads();

  if (tid < 64) {
    float v = hls[tid];
    float mx = v;
    #pragma unroll
    for (int o = 32; o; o >>= 1) mx = fmaxf(mx, __shfl_xor(mx, o));
    float e = __expf(v - mx);
    float sm = e;
    #pragma unroll
    for (int o = 32; o; o >>= 1) sm += __shfl_xor(sm, o);
    wts[tid] = e / sm;
  }
  __syncthreads();

  float kv = 0.f;
  #pragma unroll 8
  for (int a2 = 0; a2 < 64; ++a2) kv += wts[a2] * Ls[a2][tid];

  S[(size_t)m * 256 + tid] = outs[tid];
  S[(size_t)m * 256 + 128 + tid] = kv;
}

// ---------------------------------------------------------------------------
extern "C" void kernel_launch(void* const* d_in, const int* in_sizes, int n_in,
                              void* d_out, int out_size, void* d_ws, size_t ws_size,
                              hipStream_t stream) {
  const float* inputs_x  = (const float*)d_in[0];
  const int*   inputs_f  = (const int*)d_in[1];
  const float* mask_seqs = (const float*)d_in[2];
  const float* dag_emb   = (const float*)d_in[3];
  const float* embed_a   = (const float*)d_in[4];
  const float* Wih0 = (const float*)d_in[5];
  const float* Whh0 = (const float*)d_in[6];
  const float* bih0 = (const float*)d_in[7];
  const float* bhh0 = (const float*)d_in[8];
  const float* Wih1 = (const float*)d_in[9];
  const float* Whh1 = (const float*)d_in[10];
  const float* bih1 = (const float*)d_in[11];
  const float* bhh1 = (const float*)d_in[12];
  const float* fc_w = (const float*)d_in[13];
  const float* fc_b = (const float*)d_in[14];
  float* out = (float*)d_out;

  float* ws = (float*)d_ws;
  // Footprint identical to R5 (proven to fit): 5*819200 + 2457600 + 2*819200 floats.
  float* P  = ws;
  float* X  = P;                       // aliases P slot 0 (reduce in-place safe)
  float* S  = P + 819200;              // aliases P slots 1-2 (P dead after reduce)
  float* xW = ws + KSPLIT * 819200;
  float* H1 = xW + 2457600;
  float* H2 = H1 + 819200;
  // Wt (2.5 MB bf16) aliases H1+H2 (3.3 MB): dead before k_gru writes H1.
  unsigned short* Wt = (unsigned short*)H1;

  k_prep_wt<<<306, 256, 0, stream>>>(dag_emb, Wt);
  k_gemm_mfma<<<dim3(100, KSPLIT), 256, 0, stream>>>(inputs_x, Wt, P);
  k_reduce_tanh<<<800, 256, 0, stream>>>(P, X);
  k_gemm_bn<128, 0><<<dim3(200, 6), 256, 0, stream>>>(X, Wih0, bih0, nullptr, xW, 384, 384);
  k_gru<<<128, 512, 0, stream>>>(xW, Whh0, bhh0, H1);
  k_gemm_bn<128, 0><<<dim3(200, 6), 256, 0, stream>>>(H1, Wih1, bih1, nullptr, xW, 384, 384);
  k_gru<<<128, 512, 0, stream>>>(xW, Whh1, bhh1, H2);
  k_attn<<<6400, 128, 0, stream>>>(H2, inputs_f, embed_a, S);
  k_gemm_bn<256, 1><<<dim3(200, 5), 256, 0, stream>>>(S, fc_w, fc_b, mask_seqs, out, 283, 283);
}

// Round 7
// 506.618 us; speedup vs baseline: 3.1107x; 1.0246x over previous
//
#include <hip/hip_runtime.h>
#include <math.h>

#define B_DIM 128
#define T_DIM 50
#define LEAF  4880
#define A_DIM 64
#define ATTN  128
#define RNN   128
#define NC    283
#define M_TOT (B_DIM*T_DIM)   // 6400
#define KSPLIT 5
#define NCH 153               // ceil(4880/32); chunk 152 has 16 valid k
#define WT_PLANE (NCH*512*8)  // 626688 ushort per plane (hi / lo)

using short8 = __attribute__((ext_vector_type(8))) short;
using f32x4  = __attribute__((ext_vector_type(4))) float;

__device__ __forceinline__ float sigmoidf_(float x) {
  return 1.0f / (1.0f + __expf(-x));
}

// RNE fp32 -> bf16 bits
__device__ __forceinline__ unsigned short f32_to_bf16_rne(float f) {
  unsigned int u = __float_as_uint(f);
  unsigned int r = u + 0x7FFFu + ((u >> 16) & 1u);
  return (unsigned short)(r >> 16);
}
__device__ __forceinline__ float bf16_bits_to_f32(unsigned short b) {
  return __uint_as_float(((unsigned int)b) << 16);
}

// ---------------------------------------------------------------------------
// Pre-transpose W[4880,128] into MFMA B-fragment order, hi/lo bf16 planes.
// ---------------------------------------------------------------------------
__global__ __launch_bounds__(256) void k_prep_wt(
    const float* __restrict__ Wd, unsigned short* __restrict__ Wt) {
  const int u = blockIdx.x * 256 + threadIdx.x;   // 0 .. 78335 (NCH*512)
  const int c = u >> 9, rem = u & 511;
  const int nt = rem >> 6, lane = rem & 63;
  const int n = nt * 16 + (lane & 15);
  const int kb = c * 32 + ((lane >> 4) << 3);
  short8 h8, l8;
  #pragma unroll
  for (int j = 0; j < 8; ++j) {
    int k = kb + j;
    float v = (k < LEAF) ? Wd[(size_t)k * 128 + n] : 0.0f;
    unsigned short hb = f32_to_bf16_rne(v);
    unsigned short lb = f32_to_bf16_rne(v - bf16_bits_to_f32(hb));
    h8[j] = (short)hb;
    l8[j] = (short)lb;
  }
  *(short8*)&Wt[(size_t)u * 8] = h8;
  *(short8*)&Wt[(size_t)WT_PLANE + (size_t)u * 8] = l8;
}

// ---------------------------------------------------------------------------
// Big GEMM via MFMA, v2 (pipelined): P[s][6400,128] partial products.
// R6 was latency-bound (MfmaUtil 9.7 / VALU 9.6 / HBM 11.5 / occ 20.7):
// 500 blocks (~2/CU) + barrier-exposed 900cyc global latency per chunk.
// v2: BM=32 -> grid (200,KSPLIT)=1000 blocks (~4/CU, 16 waves/CU) at zero
// extra workspace, + register prefetch of chunk c+1 issued before compute(c)
// so HBM latency overlaps MFMA/ds_read of chunk c (and 3 other blocks/CU).
// hi/lo bf16 split (3 MFMA) for fp32-level accuracy. All register arrays
// indexed by unroll constants only (R4 lesson).
// Tail: 4880=32*152+16, quads 8-aligned -> (kg+8<=LEAF) is all-or-nothing.
// ---------------------------------------------------------------------------
__global__ __launch_bounds__(256) void k_gemm_mfma(
    const float* __restrict__ Ax, const unsigned short* __restrict__ Wt,
    float* __restrict__ P) {
  __shared__ __align__(16) unsigned short As[2048];  // [plane][msub][lane][8] 4 KB
  __shared__ __align__(16) unsigned short Bs[8192];  // [plane][nt][lane][8] 16 KB
  const int tid  = threadIdx.x;
  const int lane = tid & 63;
  const int w    = tid >> 6;
  const int msub = w & 1;        // M-subtile 0/1 (16 rows each)
  const int nh   = w >> 1;       // N-half 0/1 (4 nt each)
  const int M0   = blockIdx.x * 32;
  const int s    = blockIdx.y;
  const int c0   = (s * NCH) / KSPLIT;
  const int c1   = ((s + 1) * NCH) / KSPLIT;

  // A staging map (tid < 128): row am = tid>>2, k-quad aq = tid&3.
  // 4 consecutive threads read 128B contiguous per row (coalesced).
  const int am = tid >> 2;
  const int aq = tid & 3;
  const float* pA = Ax + (size_t)(M0 + am) * LEAF + aq * 8;
  const int a_slot = (((am >> 4) * 64) + (am & 15) + 16 * aq) * 8;

  f32x4 acc[4];
  #pragma unroll
  for (int i = 0; i < 4; ++i) {
    #pragma unroll
    for (int q = 0; q < 4; ++q) acc[i][q] = 0.0f;
  }

  // prefetch registers
  float4 ra0 = make_float4(0.f, 0.f, 0.f, 0.f);
  float4 ra1 = make_float4(0.f, 0.f, 0.f, 0.f);
  short8 rb0, rb1, rb2, rb3;

  // ---- prologue: load chunk c0 ----
  {
    const int c = c0;
    if (tid < 128) {
      const int kg = c * 32 + aq * 8;
      if (kg + 8 <= LEAF) {
        ra0 = *(const float4*)(pA + (size_t)c * 32);
        ra1 = *(const float4*)(pA + (size_t)c * 32 + 4);
      } else { ra0 = make_float4(0.f,0.f,0.f,0.f); ra1 = make_float4(0.f,0.f,0.f,0.f); }
    }
    const size_t cb = (size_t)c * 512;
    rb0 = *(const short8*)&Wt[((size_t)((tid      ) >> 9)) * WT_PLANE + (cb + ((tid      ) & 511)) * 8];
    rb1 = *(const short8*)&Wt[((size_t)((tid + 256) >> 9)) * WT_PLANE + (cb + ((tid + 256) & 511)) * 8];
    rb2 = *(const short8*)&Wt[((size_t)((tid + 512) >> 9)) * WT_PLANE + (cb + ((tid + 512) & 511)) * 8];
    rb3 = *(const short8*)&Wt[((size_t)((tid + 768) >> 9)) * WT_PLANE + (cb + ((tid + 768) & 511)) * 8];
  }

  for (int c = c0; c < c1; ++c) {
    // ---- store staged regs (chunk c) into LDS ----
    if (tid < 128) {
      float v[8] = {ra0.x, ra0.y, ra0.z, ra0.w, ra1.x, ra1.y, ra1.z, ra1.w};
      short8 h8, l8;
      #pragma unroll
      for (int j = 0; j < 8; ++j) {
        unsigned short hb = f32_to_bf16_rne(v[j]);
        unsigned short lb = f32_to_bf16_rne(v[j] - bf16_bits_to_f32(hb));
        h8[j] = (short)hb;
        l8[j] = (short)lb;
      }
      *(short8*)&As[a_slot] = h8;
      *(short8*)&As[1024 + a_slot] = l8;
    }
    *(short8*)&Bs[((tid      ) >> 9) * 4096 + ((tid      ) & 511) * 8] = rb0;
    *(short8*)&Bs[((tid + 256) >> 9) * 4096 + ((tid + 256) & 511) * 8] = rb1;
    *(short8*)&Bs[((tid + 512) >> 9) * 4096 + ((tid + 512) & 511) * 8] = rb2;
    *(short8*)&Bs[((tid + 768) >> 9) * 4096 + ((tid + 768) & 511) * 8] = rb3;
    __syncthreads();

    // ---- issue prefetch for chunk c+1 (overlaps compute below) ----
    if (c + 1 < c1) {
      const int cn = c + 1;
      if (tid < 128) {
        const int kg = cn * 32 + aq * 8;
        if (kg + 8 <= LEAF) {
          ra0 = *(const float4*)(pA + (size_t)cn * 32);
          ra1 = *(const float4*)(pA + (size_t)cn * 32 + 4);
        } else { ra0 = make_float4(0.f,0.f,0.f,0.f); ra1 = make_float4(0.f,0.f,0.f,0.f); }
      }
      const size_t cb = (size_t)cn * 512;
      rb0 = *(const short8*)&Wt[((size_t)((tid      ) >> 9)) * WT_PLANE + (cb + ((tid      ) & 511)) * 8];
      rb1 = *(const short8*)&Wt[((size_t)((tid + 256) >> 9)) * WT_PLANE + (cb + ((tid + 256) & 511)) * 8];
      rb2 = *(const short8*)&Wt[((size_t)((tid + 512) >> 9)) * WT_PLANE + (cb + ((tid + 512) & 511)) * 8];
      rb3 = *(const short8*)&Wt[((size_t)((tid + 768) >> 9)) * WT_PLANE + (cb + ((tid + 768) & 511)) * 8];
    }

    // ---- compute chunk c ----
    {
      short8 a_hi = *(const short8*)&As[(msub * 64 + lane) * 8];
      short8 a_lo = *(const short8*)&As[1024 + (msub * 64 + lane) * 8];
      #pragma unroll
      for (int i = 0; i < 4; ++i) {
        const int nt = nh * 4 + i;
        short8 b_hi = *(const short8*)&Bs[(nt * 64 + lane) * 8];
        short8 b_lo = *(const short8*)&Bs[4096 + (nt * 64 + lane) * 8];
        acc[i] = __builtin_amdgcn_mfma_f32_16x16x32_bf16(a_hi, b_lo, acc[i], 0, 0, 0);
        acc[i] = __builtin_amdgcn_mfma_f32_16x16x32_bf16(a_lo, b_hi, acc[i], 0, 0, 0);
        acc[i] = __builtin_amdgcn_mfma_f32_16x16x32_bf16(a_hi, b_hi, acc[i], 0, 0, 0);
      }
    }
    __syncthreads();
  }

  // epilogue: C/D layout col=lane&15, row=(lane>>4)*4+r
  float* outp = P + (size_t)s * ((size_t)M_TOT * 128);
  const int mrow = M0 + msub * 16 + ((lane >> 4) << 2);
  const int col0 = nh * 64 + (lane & 15);
  #pragma unroll
  for (int i = 0; i < 4; ++i) {
    #pragma unroll
    for (int r = 0; r < 4; ++r)
      outp[(size_t)(mrow + r) * 128 + col0 + i * 16] = acc[i][r];
  }
}

// ---------------------------------------------------------------------------
// Reduce KSPLIT partials + tanh (X aliases P slot 0; elementwise-safe).
// ---------------------------------------------------------------------------
__global__ __launch_bounds__(256) void k_reduce_tanh(
    float* __restrict__ P, float* __restrict__ X) {
  const size_t i = ((size_t)blockIdx.x * 256 + threadIdx.x) * 4;
  float4 a = *(const float4*)&P[i];
  #pragma unroll
  for (int s = 1; s < KSPLIT; ++s) {
    float4 b = *(const float4*)&P[(size_t)s * (M_TOT * 128) + i];
    a.x += b.x; a.y += b.y; a.z += b.z; a.w += b.w;
  }
  a.x = tanhf(a.x); a.y = tanhf(a.y); a.z = tanhf(a.z); a.w = tanhf(a.w);
  *(float4*)&X[i] = a;
}

// ---------------------------------------------------------------------------
// Generic small GEMM: C[M,N] = A[M,K] @ Bw[N,K]^T + bias  (opt sigmoid*mask)
// ---------------------------------------------------------------------------
template<int K, int ACT>
__global__ __launch_bounds__(256) void k_gemm_bn(
    const float* __restrict__ A, const float* __restrict__ Bw,
    const float* __restrict__ bias, const float* __restrict__ maskv,
    float* __restrict__ C, int N, int ldc) {
  __shared__ __align__(16) float Asm[32][K + 4];
  const int tid = threadIdx.x;
  const int m0 = blockIdx.x * 32;
  const int n0 = blockIdx.y * 64;
  constexpr int K4 = K / 4;

  #pragma unroll
  for (int i = 0; i < (32 * K4) / 256; ++i) {
    int idx = tid + i * 256;
    int row = idx / K4, k4 = idx % K4;
    float4 v = *(const float4*)&A[(size_t)(m0 + row) * K + k4 * 4];
    *(float4*)&Asm[row][k4 * 4] = v;
  }
  __syncthreads();

  const int n2 = tid & 31, mg = tid >> 5;
  const int n = n0 + n2 * 2;
  const int ns0 = min(n, N - 1), ns1 = min(n + 1, N - 1);
  const float* Bp0 = Bw + (size_t)ns0 * K;
  const float* Bp1 = Bw + (size_t)ns1 * K;

  float acc[4][2] = {};
  #pragma unroll 4
  for (int k = 0; k < K; k += 4) {
    float4 b0 = *(const float4*)&Bp0[k];
    float4 b1 = *(const float4*)&Bp1[k];
    #pragma unroll
    for (int r = 0; r < 4; ++r) {
      float4 a = *(const float4*)&Asm[mg * 4 + r][k];
      acc[r][0] += a.x * b0.x + a.y * b0.y + a.z * b0.z + a.w * b0.w;
      acc[r][1] += a.x * b1.x + a.y * b1.y + a.z * b1.z + a.w * b1.w;
    }
  }

  #pragma unroll
  for (int r = 0; r < 4; ++r) {
    int m = m0 + mg * 4 + r;
    #pragma unroll
    for (int c = 0; c < 2; ++c) {
      int nn = n + c;
      if (nn < N) {
        float v = acc[r][c] + bias[nn];
        if (ACT) v = sigmoidf_(v) * maskv[m];
        C[(size_t)m * ldc + nn] = v;
      }
    }
  }
}

// ---------------------------------------------------------------------------
// GRU scan v3 (R5-proven). One block per batch row; 512 threads.
// Weights pre-rotated at load (register arrays use unroll-constant indices
// only). n-gate bias INSIDE r*: n = tanh(xn + r*(Wn.h + bn)).
// ---------------------------------------------------------------------------
__global__ __launch_bounds__(512) void k_gru(
    const float* __restrict__ xW, const float* __restrict__ Whh,
    const float* __restrict__ bhh, float* __restrict__ Hout) {
  const int b = blockIdx.x;
  const int tid = threadIdx.x;
  const int j  = tid >> 2;
  const int qf = tid & 3;
  __shared__ __align__(16) float hs[2][128];

  float4 wr[8], wz[8], wn[8];
  {
    const float* pr = Whh + (size_t)j * 128 + qf * 32;
    const float* pz = Whh + (size_t)(j + 128) * 128 + qf * 32;
    const float* pn = Whh + (size_t)(j + 256) * 128 + qf * 32;
    #pragma unroll
    for (int k = 0; k < 8; ++k) {
      const int c = (k + qf * 2) & 7;   // rotation folded into the LOAD
      wr[k] = *(const float4*)(pr + c * 4);
      wz[k] = *(const float4*)(pz + c * 4);
      wn[k] = *(const float4*)(pn + c * 4);
    }
  }
  const float br = bhh[j], bz = bhh[j + 128], bn_ = bhh[j + 256];

  if (tid < 128) hs[0][tid] = 0.0f;
  const float* xwb = xW + (size_t)b * 50 * 384;
  float xr = 0.f, xz = 0.f, xn = 0.f;
  if (qf == 0) { xr = xwb[j]; xz = xwb[128 + j]; xn = xwb[256 + j]; }
  __syncthreads();

  int cur = 0;
  for (int t = 0; t < 50; ++t) {
    float nxr = 0.f, nxz = 0.f, nxn = 0.f;
    if (qf == 0 && t + 1 < 50) {
      const float* xwn = xwb + (size_t)(t + 1) * 384;
      nxr = xwn[j]; nxz = xwn[128 + j]; nxn = xwn[256 + j];
    }

    float ar = 0.f, az = 0.f, an = 0.f;
    #pragma unroll
    for (int k = 0; k < 8; ++k) {
      const int c = (k + qf * 2) & 7;   // runtime -> LDS address only
      float4 hv = *(const float4*)&hs[cur][qf * 32 + c * 4];
      ar += wr[k].x * hv.x + wr[k].y * hv.y + wr[k].z * hv.z + wr[k].w * hv.w;
      az += wz[k].x * hv.x + wz[k].y * hv.y + wz[k].z * hv.z + wz[k].w * hv.w;
      an += wn[k].x * hv.x + wn[k].y * hv.y + wn[k].z * hv.z + wn[k].w * hv.w;
    }
    ar += __shfl_xor(ar, 1); ar += __shfl_xor(ar, 2);
    az += __shfl_xor(az, 1); az += __shfl_xor(az, 2);
    an += __shfl_xor(an, 1); an += __shfl_xor(an, 2);

    if (qf == 0) {
      float r = sigmoidf_(xr + ar + br);
      float z = sigmoidf_(xz + az + bz);
      float nn = tanhf(xn + r * (an + bn_));   // bias INSIDE r*
      float h = (1.f - z) * nn + z * hs[cur][j];
      hs[cur ^ 1][j] = h;
      Hout[(size_t)(b * 50 + t) * 128 + j] = h;
    }
    __syncthreads();
    cur ^= 1;
    xr = nxr; xz = nxz; xn = nxn;
  }
}

// ---------------------------------------------------------------------------
// Attention: per (b,t) block (6400 blocks, 128 threads).
// ---------------------------------------------------------------------------
__global__ __launch_bounds__(128) void k_attn(
    const float* __restrict__ H2, const int* __restrict__ F,
    const float* __restrict__ emb, float* __restrict__ S) {
  const int m = blockIdx.x;
  const int tid = threadIdx.x;
  __shared__ __align__(16) float outs[128];
  __shared__ __align__(16) float Ls[64][132];
  __shared__ float hls[64];
  __shared__ float wts[64];
  __shared__ int fs[64];

  outs[tid] = H2[(size_t)m * 128 + tid];
  if (tid < 64) fs[tid] = F[(size_t)m * 64 + tid];
  __syncthreads();

  #pragma unroll
  for (int i = 0; i < 16; ++i) {
    int idx = tid + i * 128;
    int a = idx >> 5, c4 = idx & 31;
    float4 v = *(const float4*)&emb[(size_t)fs[a] * 128 + c4 * 4];
    *(float4*)&Ls[a][c4 * 4] = v;
  }
  __syncthreads();

  {
    const int a = tid >> 1, hf = tid & 1;
    float sum = 0.f;
    #pragma unroll
    for (int j = 0; j < 16; ++j) {
      float4 lv = *(const float4*)&Ls[a][hf * 64 + j * 4];
      float4 ov = *(const float4*)&outs[hf * 64 + j * 4];
      sum += lv.x * ov.x + lv.y * ov.y + lv.z * ov.z + lv.w * ov.w;
    }
    float other = __shfl_xor(sum, 1);
    sum += other;
    if (hf == 0) hls[a] = sum + (fs[a] > 0 ? 0.0f : -1e30f);
  }
  __syncthreads();

  if (tid < 64) {
    float v = hls[tid];
    float mx = v;
    #pragma unroll
    for (int o = 32; o; o >>= 1) mx = fmaxf(mx, __shfl_xor(mx, o));
    float e = __expf(v - mx);
    float sm = e;
    #pragma unroll
    for (int o = 32; o; o >>= 1) sm += __shfl_xor(sm, o);
    wts[tid] = e / sm;
  }
  __syncthreads();

  float kv = 0.f;
  #pragma unroll 8
  for (int a2 = 0; a2 < 64; ++a2) kv += wts[a2] * Ls[a2][tid];

  S[(size_t)m * 256 + tid] = outs[tid];
  S[(size_t)m * 256 + 128 + tid] = kv;
}

// ---------------------------------------------------------------------------
extern "C" void kernel_launch(void* const* d_in, const int* in_sizes, int n_in,
                              void* d_out, int out_size, void* d_ws, size_t ws_size,
                              hipStream_t stream) {
  const float* inputs_x  = (const float*)d_in[0];
  const int*   inputs_f  = (const int*)d_in[1];
  const float* mask_seqs = (const float*)d_in[2];
  const float* dag_emb   = (const float*)d_in[3];
  const float* embed_a   = (const float*)d_in[4];
  const float* Wih0 = (const float*)d_in[5];
  const float* Whh0 = (const float*)d_in[6];
  const float* bih0 = (const float*)d_in[7];
  const float* bhh0 = (const float*)d_in[8];
  const float* Wih1 = (const float*)d_in[9];
  const float* Whh1 = (const float*)d_in[10];
  const float* bih1 = (const float*)d_in[11];
  const float* bhh1 = (const float*)d_in[12];
  const float* fc_w = (const float*)d_in[13];
  const float* fc_b = (const float*)d_in[14];
  float* out = (float*)d_out;

  float* ws = (float*)d_ws;
  // Footprint identical to R5/R6 (proven): 5*819200 + 2457600 + 2*819200 floats.
  float* P  = ws;
  float* X  = P;                       // aliases P slot 0 (reduce in-place safe)
  float* S  = P + 819200;              // aliases P slots 1-2 (P dead after reduce)
  float* xW = ws + KSPLIT * 819200;
  float* H1 = xW + 2457600;
  float* H2 = H1 + 819200;
  // Wt (2.5 MB bf16) aliases H1+H2 (6.5 MB): dead before k_gru writes H1.
  unsigned short* Wt = (unsigned short*)H1;

  k_prep_wt<<<306, 256, 0, stream>>>(dag_emb, Wt);
  k_gemm_mfma<<<dim3(200, KSPLIT), 256, 0, stream>>>(inputs_x, Wt, P);
  k_reduce_tanh<<<800, 256, 0, stream>>>(P, X);
  k_gemm_bn<128, 0><<<dim3(200, 6), 256, 0, stream>>>(X, Wih0, bih0, nullptr, xW, 384, 384);
  k_gru<<<128, 512, 0, stream>>>(xW, Whh0, bhh0, H1);
  k_gemm_bn<128, 0><<<dim3(200, 6), 256, 0, stream>>>(H1, Wih1, bih1, nullptr, xW, 384, 384);
  k_gru<<<128, 512, 0, stream>>>(xW, Whh1, bhh1, H2);
  k_attn<<<6400, 128, 0, stream>>>(H2, inputs_f, embed_a, S);
  k_gemm_bn<256, 1><<<dim3(200, 5), 256, 0, stream>>>(S, fc_w, fc_b, mask_seqs, out, 283, 283);
}